// Round 9
// baseline (238.389 us; speedup 1.0000x reference)
//
#include <hip/hip_runtime.h>
#include <cstddef>

// AttentionLayerPooler: out[m,n] = sum_l softmax(logits)[m,l] * in[l,n]
// LT=36, LS=28, slice = 2,097,152 fp32. HBM floor ~120-170 us.
//
// R5-R8 post-mortem: kernel is LDS-PIPE-bound, not HBM/occupancy-bound.
// Per tile per wave: 63 broadcast ds_read_b128 (weights) = 756 of ~1008
// LDS cycles; x4 waves = 4032 cyc/tile on ONE LDS pipe vs HBM 2208.
// 128 tiles/CU x 4032 = 215 us == observed 230. Model also retrodicts R5.
// R9: weights via s_load into SGPRs (idle SMEM pipe, K$-cached).
//   - pre-kernel softmaxes both tables into d_ws, layout [l/4][m][j] so a
//     7-row band per lb is 7 dwordx4 s_loads at compile-time offsets.
//   - FMA reads weight from SGPR directly (1 SGPR operand: legal).
//   - LDS weight tables deleted -> 36.9 KB -> 4 blocks/CU (16 waves).
//   - s_loads use lgkmcnt, so R8's counted-vmcnt scheme stays valid.

constexpr int LT = 36;
constexpr int LS = 28;
constexpr int N2 = 1048576;            // float2 per layer slice
constexpr int TILE = 64;               // float2 cols per tile
constexpr int TPT = N2 / TILE;         // 16384 tiles per tensor
constexpr int NTILES = 2 * TPT;        // 32768
constexpr int TPB = 256;               // 4 waves
constexpr int NBLOCKS = 1024;          // 4 blocks/CU, 32 tiles/block exactly
constexpr int W_TENSOR_STRIDE = 9 * LS * 4;  // 1008 floats per weight table

typedef __attribute__((ext_vector_type(4))) float f32x4;

// Pre-kernel: softmax the two 28x36 logit tables into d_ws, layout
// ws[tensor][l>>2][m][l&3] (m-stride 16 B) so the main kernel can fetch
// any 7-m band for one lb as 7 contiguous-strided s_load_dwordx4.
__global__ __launch_bounds__(64) void softmax_kernel(
    const float* __restrict__ lgk, const float* __restrict__ lgv,
    float* __restrict__ ws)
{
    const int t = threadIdx.x;
    const int isv = t >> 5;
    const int m = t & 31;
    if (m >= LS) return;
    const float* row = (isv ? lgv : lgk) + m * LT;
    float mx = -3.4e38f;
    for (int l = 0; l < LT; ++l) mx = fmaxf(mx, row[l]);
    float s = 0.f;
    for (int l = 0; l < LT; ++l) s += expf(row[l] - mx);
    const float inv = 1.0f / s;
    float* o = ws + isv * W_TENSOR_STRIDE;
    for (int l = 0; l < LT; ++l)
        o[(l >> 2) * (LS * 4) + m * 4 + (l & 3)] = expf(row[l] - mx) * inv;
}

// One lb-block (4 layers): 4 data ds_read_b64 + 7 weight s_load_dwordx4
// (SMEM pipe, K$-hot after tile 0) + 56 FMAs with SGPR weight operand.
template<int LB>
__device__ __forceinline__ void do_lb(const float* wq,
                                      const float2 (*cur)[TILE],
                                      int lane, float2* acc)
{
    float2 d[4];
#pragma unroll
    for (int j = 0; j < 4; ++j) d[j] = cur[4 * LB + j][lane];

    f32x4 w0, w1, w2, w3, w4, w5, w6;
    asm volatile(
        "s_load_dwordx4 %0, %[b], %[o0]\n\t"
        "s_load_dwordx4 %1, %[b], %[o1]\n\t"
        "s_load_dwordx4 %2, %[b], %[o2]\n\t"
        "s_load_dwordx4 %3, %[b], %[o3]\n\t"
        "s_load_dwordx4 %4, %[b], %[o4]\n\t"
        "s_load_dwordx4 %5, %[b], %[o5]\n\t"
        "s_load_dwordx4 %6, %[b], %[o6]\n\t"
        "s_waitcnt lgkmcnt(0)"
        : "=s"(w0), "=s"(w1), "=s"(w2), "=s"(w3), "=s"(w4), "=s"(w5), "=s"(w6)
        : [b] "s"(wq),
          [o0] "i"(LB * 448 + 0),  [o1] "i"(LB * 448 + 16),
          [o2] "i"(LB * 448 + 32), [o3] "i"(LB * 448 + 48),
          [o4] "i"(LB * 448 + 64), [o5] "i"(LB * 448 + 80),
          [o6] "i"(LB * 448 + 96));

    const f32x4 W[7] = {w0, w1, w2, w3, w4, w5, w6};
#pragma unroll
    for (int k = 0; k < 7; ++k) {
        acc[k].x = fmaf(W[k].x, d[0].x, acc[k].x);
        acc[k].y = fmaf(W[k].x, d[0].y, acc[k].y);
        acc[k].x = fmaf(W[k].y, d[1].x, acc[k].x);
        acc[k].y = fmaf(W[k].y, d[1].y, acc[k].y);
        acc[k].x = fmaf(W[k].z, d[2].x, acc[k].x);
        acc[k].y = fmaf(W[k].z, d[2].y, acc[k].y);
        acc[k].x = fmaf(W[k].w, d[3].x, acc[k].x);
        acc[k].y = fmaf(W[k].w, d[3].y, acc[k].y);
    }
}

__global__ __launch_bounds__(TPB) void pool_kernel(
    const float2* __restrict__ ks,
    const float2* __restrict__ vs,
    const float* __restrict__ ws,
    float2* __restrict__ out)
{
    // Depth-2 staging only (no LDS weights): 36,864 B -> 4 blocks/CU.
    __shared__ float2 smA[LT][TILE];
    __shared__ float2 smB[LT][TILE];

    const int tid  = threadIdx.x;
    const int wv   = tid >> 6;
    const int lane = tid & 63;
    const int wvu  = __builtin_amdgcn_readfirstlane(wv);  // provably uniform
    const int m0   = 7 * wvu;  // wave's 7 output layers

    // chunk i covers layers 2i,2i+1; lanes 32-63 land in row 2i+1.
    const size_t lofs = (size_t)(lane >> 5) * N2 + (size_t)((lane & 31) << 1);

    auto stage = [&](float2 (*buf)[TILE], int t) {
        const float2* src = (t >= TPT) ? vs : ks;
        const size_t c0 = (size_t)(t & (TPT - 1)) * TILE;
        for (int i = wv; i < 18; i += 4) {
            const float2* g = src + (size_t)(2 * i) * N2 + c0 + lofs;
            __builtin_amdgcn_global_load_lds(
                (const __attribute__((address_space(1))) void*)g,
                (__attribute__((address_space(3))) void*)&buf[2 * i][0],
                16, 0, 0);
        }
    };

    int t = blockIdx.x;
    stage(smA, t);
    __syncthreads();  // full drain once: tile 0 ready

    float2 (*cur)[TILE] = smA;
    float2 (*nxt)[TILE] = smB;

    for (;;) {
        const int tn = t + NBLOCKS;
        const bool more = (tn < NTILES);

        // A) Prefetch next tile (buffer freed by barrier E).
        if (more) stage(nxt, tn);

        // B) Counted wait: clear only the oldest batch = loads(t); the
        //    prefetch and prior stores stay in flight across the barrier.
        if (more) asm volatile("s_waitcnt vmcnt(11)" ::: "memory");
        else      asm volatile("s_waitcnt vmcnt(7)"  ::: "memory");
        __builtin_amdgcn_sched_barrier(0);
        asm volatile("s_barrier" ::: "memory");

        const bool isv = (t >= TPT);
        const float* wq = ws + (isv ? W_TENSOR_STRIDE : 0) + m0 * 4;
        const size_t c0 = (size_t)(t & (TPT - 1)) * TILE;
        float2* dstb = out + (isv ? (size_t)LS * N2 : (size_t)0);

        // C) Compute tile t. LDS pipe now carries data reads only
        //    (36 b64/wave/tile); weights ride the SMEM pipe.
        float2 acc[7];
#pragma unroll
        for (int k = 0; k < 7; ++k) acc[k] = make_float2(0.f, 0.f);

        do_lb<0>(wq, cur, lane, acc);
        do_lb<1>(wq, cur, lane, acc);
        do_lb<2>(wq, cur, lane, acc);
        do_lb<3>(wq, cur, lane, acc);
        do_lb<4>(wq, cur, lane, acc);
        do_lb<5>(wq, cur, lane, acc);
        do_lb<6>(wq, cur, lane, acc);
        do_lb<7>(wq, cur, lane, acc);
        do_lb<8>(wq, cur, lane, acc);

        // D) Stores: fire-and-forget, drain under next tile's compute.
#pragma unroll
        for (int k = 0; k < 7; ++k) {
            dstb[(size_t)(m0 + k) * N2 + c0 + lane] = acc[k];
        }

        if (!more) break;

        // E) Raw barrier (no drain): cur is now free for the next DMA.
        asm volatile("s_barrier" ::: "memory");

        t = tn;
        float2 (*tmp)[TILE] = cur; cur = nxt; nxt = tmp;
    }
}

extern "C" void kernel_launch(void* const* d_in, const int* in_sizes, int n_in,
                              void* d_out, int out_size, void* d_ws, size_t ws_size,
                              hipStream_t stream)
{
    const float2* ks  = (const float2*)d_in[0];
    const float2* vs  = (const float2*)d_in[1];
    const float* lgk  = (const float*)d_in[2];
    const float* lgv  = (const float*)d_in[3];
    float* ws = (float*)d_ws;          // 8064 B of scratch for weights
    float2* out = (float2*)d_out;

    hipLaunchKernelGGL(softmax_kernel, dim3(1), dim3(64), 0, stream,
                       lgk, lgv, ws);
    hipLaunchKernelGGL(pool_kernel, dim3(NBLOCKS), dim3(TPB), 0, stream,
                       ks, vs, ws, out);
}